// Round 18
// baseline (186.549 us; speedup 1.0000x reference)
//
#include <hip/hip_runtime.h>

#define TOK 4096
#define EMB 1024

typedef __attribute__((ext_vector_type(8))) short s16x8;
typedef __attribute__((ext_vector_type(4))) float f32x4;

__device__ __forceinline__ unsigned short f2bf(float f) {
  union { float f; unsigned int u; } v; v.f = f;
  unsigned int r = v.u + 0x7FFFu + ((v.u >> 16) & 1u);
  return (unsigned short)(r >> 16);
}
__device__ __forceinline__ float bf2f(unsigned short u) {
  union { unsigned int u; float f; } v; v.u = ((unsigned int)u) << 16; return v.f;
}

#define GLOAD_LDS16(g, l) __builtin_amdgcn_global_load_lds( \
    (const __attribute__((address_space(1))) void*)(g), \
    (__attribute__((address_space(3))) void*)(l), 16, 0, 0)

// =================== 256x256 GEMM, BK=64 (round-9 core, FROZEN at ~868 TF)
// 1 block/CU (128KB LDS). See round-17 source for full history/lessons.
template<int RELU, int PART, int NT, int VTR>
__global__ __launch_bounds__(512)
void gemm256(const unsigned short* __restrict__ A,
             const unsigned short* __restrict__ B,
             const float* __restrict__ bias,
             unsigned short* __restrict__ C, int M, int N, int K,
             unsigned short* __restrict__ vT)
{
  __shared__ unsigned short lds[2][2][128 * 128];
  const int tid = threadIdx.x;
  const int lane = tid & 63;
  const int w = tid >> 6;
  const int wr = w >> 2, wc = w & 3;
  const int l15 = lane & 15, lhi = lane >> 4;
  const int nbm = M >> 8;
  const int bm = blockIdx.x % nbm, bn = blockIdx.x / nbm;
  const int m0 = bm << 8, n0 = bn << 8;
  const int k0 = blockIdx.y * (NT * 64);

  const char* Abase = (const char*)(A + (size_t)m0 * K) + (size_t)k0 * 2;
  const char* Bbase = (const char*)(B + (size_t)n0 * K) + (size_t)k0 * 2;
  const size_t rowb = (size_t)K * 2;

  const int srt = tid >> 3;
  const int sccx = ((tid & 7) << 4) ^ ((srt & 7) << 4);
  const char* gA = Abase + (size_t)srt * rowb + sccx;
  const char* gB = Bbase + (size_t)srt * rowb + sccx;

  auto STAGE_A = [&](int ktl, int h, int p) {
    char* d = (char*)&lds[0][0][0] + p * 32768 + h * 16384 + (w << 10);
    const char* g = gA + (size_t)(h * 128) * rowb + ktl * 128;
    GLOAD_LDS16(g, d);
    GLOAD_LDS16(g + 64 * rowb, d + 8192);
  };
  auto STAGE_B = [&](int ktl, int h, int p) {
    char* d = (char*)&lds[1][0][0] + p * 32768 + h * 16384 + (w << 10);
    const char* g = gB + (size_t)(h * 128) * rowb + ktl * 128;
    GLOAD_LDS16(g, d);
    GLOAD_LDS16(g + 64 * rowb, d + 8192);
  };

  const int rdxor = (l15 & 7) << 4;
  const char* pA0 = (const char*)&lds[0][0][0] + (wr * 128 + l15) * 128 + ((0 * 64 + lhi * 16) ^ rdxor);
  const char* pA1 = (const char*)&lds[0][0][0] + (wr * 128 + l15) * 128 + ((1 * 64 + lhi * 16) ^ rdxor);
  const char* pB0 = (const char*)&lds[1][0][0] + (wc * 64 + l15) * 128 + ((0 * 64 + lhi * 16) ^ rdxor);
  const char* pB1 = (const char*)&lds[1][0][0] + (wc * 64 + l15) * 128 + ((1 * 64 + lhi * 16) ^ rdxor);

  f32x4 acc[8][4];
#pragma unroll
  for (int mf = 0; mf < 8; ++mf)
#pragma unroll
    for (int nf = 0; nf < 4; ++nf)
#pragma unroll
      for (int j = 0; j < 4; ++j) acc[mf][nf][j] = 0.f;

  STAGE_A(0, 0, 0); STAGE_A(0, 1, 0);
  STAGE_B(0, 0, 0); STAGE_B(0, 1, 0);
  STAGE_A(1, 0, 1); STAGE_A(1, 1, 1);
  STAGE_B(1, 0, 1);
  asm volatile("s_waitcnt vmcnt(6)" ::: "memory");
  __builtin_amdgcn_s_barrier();

  s16x8 af[8][2], bf[4][2];

#pragma unroll
  for (int kt = 0; kt < NT; ++kt) {
    const int P = (kt & 1) << 15;
    const int p = kt & 1;

#pragma unroll
    for (int mi = 0; mi < 4; ++mi) {
      af[mi][0] = *(const s16x8*)(pA0 + mi * 2048 + P);
      af[mi][1] = *(const s16x8*)(pA1 + mi * 2048 + P);
    }
#pragma unroll
    for (int ni = 0; ni < 2; ++ni) {
      bf[ni][0] = *(const s16x8*)(pB0 + ni * 2048 + P);
      bf[ni][1] = *(const s16x8*)(pB1 + ni * 2048 + P);
    }
#pragma unroll
    for (int mi = 4; mi < 8; ++mi) {
      af[mi][0] = *(const s16x8*)(pA0 + mi * 2048 + P);
      af[mi][1] = *(const s16x8*)(pA1 + mi * 2048 + P);
    }
#pragma unroll
    for (int ni = 2; ni < 4; ++ni) {
      bf[ni][0] = *(const s16x8*)(pB0 + ni * 2048 + P);
      bf[ni][1] = *(const s16x8*)(pB1 + ni * 2048 + P);
    }

    if (kt + 1 < NT) STAGE_B(kt + 1, 1, p ^ 1);

    __builtin_amdgcn_s_setprio(1);
#pragma unroll
    for (int mi = 0; mi < 4; ++mi)
#pragma unroll
      for (int ni = 0; ni < 2; ++ni)
#pragma unroll
        for (int ks = 0; ks < 2; ++ks)
          acc[mi][ni] = __builtin_amdgcn_mfma_f32_16x16x32_bf16(af[mi][ks], bf[ni][ks], acc[mi][ni], 0, 0, 0);
#pragma unroll
    for (int mi = 4; mi < 8; ++mi)
#pragma unroll
      for (int ni = 0; ni < 2; ++ni)
#pragma unroll
        for (int ks = 0; ks < 2; ++ks)
          acc[mi][ni] = __builtin_amdgcn_mfma_f32_16x16x32_bf16(af[mi][ks], bf[ni][ks], acc[mi][ni], 0, 0, 0);
#pragma unroll
    for (int mi = 0; mi < 4; ++mi)
#pragma unroll
      for (int ni = 2; ni < 4; ++ni)
#pragma unroll
        for (int ks = 0; ks < 2; ++ks)
          acc[mi][ni] = __builtin_amdgcn_mfma_f32_16x16x32_bf16(af[mi][ks], bf[ni][ks], acc[mi][ni], 0, 0, 0);
#pragma unroll
    for (int mi = 4; mi < 8; ++mi)
#pragma unroll
      for (int ni = 2; ni < 4; ++ni)
#pragma unroll
        for (int ks = 0; ks < 2; ++ks)
          acc[mi][ni] = __builtin_amdgcn_mfma_f32_16x16x32_bf16(af[mi][ks], bf[ni][ks], acc[mi][ni], 0, 0, 0);
    __builtin_amdgcn_s_setprio(0);

    __builtin_amdgcn_s_barrier();

    if (kt + 2 < NT) {
      STAGE_A(kt + 2, 0, p);
      STAGE_A(kt + 2, 1, p);
      STAGE_B(kt + 2, 0, p);
    }

    if (kt + 1 < NT) {
      if (kt + 2 < NT) asm volatile("s_waitcnt vmcnt(6)" ::: "memory");
      else             asm volatile("s_waitcnt vmcnt(0)" ::: "memory");
      __builtin_amdgcn_s_barrier();
    }
  }

  unsigned short* Cw = PART ? C + (size_t)blockIdx.y * M * N : C;
#pragma unroll
  for (int mf = 0; mf < 8; ++mf) {
    const int row = m0 + wr * 128 + mf * 16 + lhi * 4;
#pragma unroll
    for (int nf = 0; nf < 4; ++nf) {
      const int col = n0 + wc * 64 + nf * 16 + l15;
      const float bv = PART ? 0.f : bias[col];
      const bool vthird = VTR && (col >= 2048);
      ushort4 pk;
#pragma unroll
      for (int j = 0; j < 4; ++j) {
        float v = acc[mf][nf][j] + bv;
        if (RELU) v = fmaxf(v, 0.f);
        const unsigned short bb = f2bf(v);
        if (!vthird)
          Cw[(size_t)(row + j) * N + col] = bb;
        else { if (j == 0) pk.x = bb; else if (j == 1) pk.y = bb; else if (j == 2) pk.z = bb; else pk.w = bb; }
      }
      if (vthird) {
        const int dcol = col - 2048;
        *(ushort4*)(vT + (size_t)dcol * 4096 + row) = pk;
      }
    }
  }
}

// =================== 256x256 GEMM, BK=32 EXPERIMENT: 64KB LDS -> 2 blocks/CU
// Round-18 theory: the 5 falsified schedule fixes all kept 1 block/CU; m97's
// naive kernel at 3 blocks/CU matches our tuned 1-block 868 TF -> co-residency
// IS the pipeline (m114). BK=32 halves LDS to 64KB -> 2 blocks/CU (VGPR 128 x
// 16 waves fits exactly). Swizzle (64B rows, 4 slots): LDS[r][s] holds global
// slot s ^ ((r>>1)&3); read slot = lhi ^ ((r>>1)&3) (2-way bank alias = free,
// m136); 16-row fragment stride keeps (r>>1)&3 invariant -> hoisted bases.
// Ledger: 4 gloads/tile {P1: HB1(kt+1)->p^1 | mid-barrier | HA0,HA1,HB0(kt+2)
// ->p}; gate vmcnt(3) (3 newest = kt+2 stages); prologue 7 loads, vmcnt(3).
// Applied ONLY to MLP1 this round; QKV/MLP2-sk stay BK64 as in-run controls.
template<int RELU, int NT>
__global__ __launch_bounds__(512)
void gemm256_b32(const unsigned short* __restrict__ A,
                 const unsigned short* __restrict__ B,
                 const float* __restrict__ bias,
                 unsigned short* __restrict__ C, int M, int N, int K)
{
  __shared__ char lds[65536];   // [matrix 32768][buf 16384]: A at 0, B at 32768
  const int tid = threadIdx.x;
  const int lane = tid & 63;
  const int w = tid >> 6;
  const int wr = w >> 2, wc = w & 3;
  const int l15 = lane & 15, lhi = lane >> 4;
  const int nbm = M >> 8;
  const int bm = blockIdx.x % nbm, bn = blockIdx.x / nbm;
  const int m0 = bm << 8, n0 = bn << 8;

  const char* Abase = (const char*)(A + (size_t)m0 * K);
  const char* Bbase = (const char*)(B + (size_t)n0 * K);
  const size_t rowb = (size_t)K * 2;

  // staging: thread t covers half-tile row t>>2 (128 rows), slot t&3;
  // source slot pre-XOR'd: (t&3) ^ ((t>>3)&3)  [= (row>>1)&3]
  const int srt = tid >> 2;
  const int sccx = (((tid & 3) ^ ((tid >> 3) & 3)) << 4);
  const char* gA = Abase + (size_t)srt * rowb + sccx;
  const char* gB = Bbase + (size_t)srt * rowb + sccx;

  auto STAGE_A = [&](int ktl, int h, int p) {
    char* d = lds + p * 16384 + h * 8192 + (w << 10);
    GLOAD_LDS16(gA + (size_t)(h * 128) * rowb + ktl * 64, d);
  };
  auto STAGE_B = [&](int ktl, int h, int p) {
    char* d = lds + 32768 + p * 16384 + h * 8192 + (w << 10);
    GLOAD_LDS16(gB + (size_t)(h * 128) * rowb + ktl * 64, d);
  };

  // read bases: row r, byte = r*64 + ((lhi ^ ((r>>1)&3))<<4); fragment adders
  // mi*16 rows = mi*1024 bytes keep (r>>1)&3 invariant; buf toggle +16384.
  {
  }
  const int rA = wr * 128 + l15;
  const int rB = wc * 64 + l15;
  const char* pA = lds + rA * 64 + ((lhi ^ ((rA >> 1) & 3)) << 4);
  const char* pB = lds + 32768 + rB * 64 + ((lhi ^ ((rB >> 1) & 3)) << 4);

  f32x4 acc[8][4];
#pragma unroll
  for (int mf = 0; mf < 8; ++mf)
#pragma unroll
    for (int nf = 0; nf < 4; ++nf)
#pragma unroll
      for (int j = 0; j < 4; ++j) acc[mf][nf][j] = 0.f;

  // prologue: tile0 {A0,A1,B0,B1} + tile1 {A0,A1,B0} = 7 loads
  STAGE_A(0, 0, 0); STAGE_A(0, 1, 0);
  STAGE_B(0, 0, 0); STAGE_B(0, 1, 0);
  STAGE_A(1, 0, 1); STAGE_A(1, 1, 1);
  STAGE_B(1, 0, 1);
  asm volatile("s_waitcnt vmcnt(3)" ::: "memory");
  __builtin_amdgcn_s_barrier();

  s16x8 af[8], bf[4];

#pragma unroll
  for (int kt = 0; kt < NT; ++kt) {
    const int P = (kt & 1) << 14;   // buf toggle 16384
    const int p = kt & 1;

#pragma unroll
    for (int mi = 0; mi < 8; ++mi) af[mi] = *(const s16x8*)(pA + mi * 1024 + P);
#pragma unroll
    for (int ni = 0; ni < 4; ++ni) bf[ni] = *(const s16x8*)(pB + ni * 1024 + P);

    if (kt + 1 < NT) STAGE_B(kt + 1, 1, p ^ 1);

    __builtin_amdgcn_s_setprio(1);
#pragma unroll
    for (int mi = 0; mi < 8; ++mi)
#pragma unroll
      for (int ni = 0; ni < 4; ++ni)
        acc[mi][ni] = __builtin_amdgcn_mfma_f32_16x16x32_bf16(af[mi], bf[ni], acc[mi][ni], 0, 0, 0);
    __builtin_amdgcn_s_setprio(0);

    __builtin_amdgcn_s_barrier();

    if (kt + 2 < NT) {
      STAGE_A(kt + 2, 0, p);
      STAGE_A(kt + 2, 1, p);
      STAGE_B(kt + 2, 0, p);
    }

    if (kt + 1 < NT) {
      if (kt + 2 < NT) asm volatile("s_waitcnt vmcnt(3)" ::: "memory");
      else             asm volatile("s_waitcnt vmcnt(0)" ::: "memory");
      __builtin_amdgcn_s_barrier();
    }
  }

  // epilogue: bias (+relu) -> bf16
#pragma unroll
  for (int mf = 0; mf < 8; ++mf) {
    const int row = m0 + wr * 128 + mf * 16 + lhi * 4;
#pragma unroll
    for (int nf = 0; nf < 4; ++nf) {
      const int col = n0 + wc * 64 + nf * 16 + l15;
      const float bv = bias[col];
#pragma unroll
      for (int j = 0; j < 4; ++j) {
        float v = acc[mf][nf][j] + bv;
        if (RELU) v = fmaxf(v, 0.f);
        C[(size_t)(row + j) * N + col] = f2bf(v);
      }
    }
  }
}

// ---------------- reduce split-K partials + bias + residual(bf16) -> fp32 out
__global__ __launch_bounds__(256)
void reduce_add(const unsigned short* __restrict__ part, const unsigned short* __restrict__ res,
                const float* __restrict__ bias, float* __restrict__ out,
                int MN, int N, int S)
{
  const int i4 = (blockIdx.x * 256 + threadIdx.x) * 4;
  if (i4 >= MN) return;
  const int col = i4 & (N - 1);
  const ushort4 r = *(const ushort4*)(res + i4);
  float4 v;
  v.x = bf2f(r.x) + bias[col];
  v.y = bf2f(r.y) + bias[col + 1];
  v.z = bf2f(r.z) + bias[col + 2];
  v.w = bf2f(r.w) + bias[col + 3];
  for (int s = 0; s < S; ++s) {
    const ushort4 p = *(const ushort4*)(part + (size_t)s * MN + i4);
    v.x += bf2f(p.x); v.y += bf2f(p.y); v.z += bf2f(p.z); v.w += bf2f(p.w);
  }
  *(float4*)(out + i4) = v;
}

// ---------------- reduce out-proj partials + bias + residual, then LayerNorm2
__global__ __launch_bounds__(256)
void reduce_ln(const unsigned short* __restrict__ part, const float* __restrict__ x,
               const float* __restrict__ ob, const float* __restrict__ ln_w,
               const float* __restrict__ ln_b, unsigned short* __restrict__ h2,
               unsigned short* __restrict__ m_in, int S)
{
  const int row = blockIdx.x;
  const int t = threadIdx.x;
  const size_t off = (size_t)row * EMB + t * 4;
  float4 v = *(const float4*)(x + off);
  const float4 obv = ((const float4*)ob)[t];
  v.x += obv.x; v.y += obv.y; v.z += obv.z; v.w += obv.w;
  for (int s = 0; s < S; ++s) {
    const ushort4 p = *(const ushort4*)(part + (size_t)s * TOK * EMB + off);
    v.x += bf2f(p.x); v.y += bf2f(p.y); v.z += bf2f(p.z); v.w += bf2f(p.w);
  }
  ushort4 hb;
  hb.x = f2bf(v.x); hb.y = f2bf(v.y); hb.z = f2bf(v.z); hb.w = f2bf(v.w);
  *(ushort4*)(h2 + off) = hb;

  float s1 = v.x + v.y + v.z + v.w;
  float sq = v.x * v.x + v.y * v.y + v.z * v.z + v.w * v.w;
#pragma unroll
  for (int o = 1; o < 64; o <<= 1) { s1 += __shfl_xor(s1, o); sq += __shfl_xor(sq, o); }
  __shared__ float red[8];
  if ((t & 63) == 0) { red[t >> 6] = s1; red[4 + (t >> 6)] = sq; }
  __syncthreads();
  s1 = red[0] + red[1] + red[2] + red[3];
  sq = red[4] + red[5] + red[6] + red[7];
  const float mu = s1 * (1.f / EMB);
  const float rs = rsqrtf(sq * (1.f / EMB) - mu * mu + 1e-5f);
  const float4 wv = ((const float4*)ln_w)[t];
  const float4 bv = ((const float4*)ln_b)[t];
  ushort4 o;
  o.x = f2bf((v.x - mu) * rs * wv.x + bv.x);
  o.y = f2bf((v.y - mu) * rs * wv.y + bv.y);
  o.z = f2bf((v.z - mu) * rs * wv.z + bv.z);
  o.w = f2bf((v.w - mu) * rs * wv.w + bv.w);
  ((ushort4*)(m_in + (size_t)row * EMB))[t] = o;
}

// ---------------- prep: weight cvt (4 matrices) + LayerNorm1, one launch
#define Q0 786432
#define Q1 (Q0 + 262144)
#define Q2 (Q1 + 1048576)
#define Q3 (Q2 + 1048576)
#define CVT_BLOCKS (Q3 / 256)   // 12288
__global__ __launch_bounds__(256)
void prep(const float* __restrict__ w0, const float* __restrict__ w1s,
          const float* __restrict__ w2s, const float* __restrict__ w3s,
          unsigned short* __restrict__ d0, unsigned short* __restrict__ d1,
          unsigned short* __restrict__ d2, unsigned short* __restrict__ d3,
          const float* __restrict__ x, const float* __restrict__ ln_w,
          const float* __restrict__ ln_b, unsigned short* __restrict__ h)
{
  __shared__ float red[8];
  const int bid = blockIdx.x;
  const int t = threadIdx.x;
  if (bid < CVT_BLOCKS) {
    const int i = bid * 256 + t;
    const float* s; unsigned short* d; int off;
    if (i < Q0)      { s = w0;  d = d0; off = i; }
    else if (i < Q1) { s = w1s; d = d1; off = i - Q0; }
    else if (i < Q2) { s = w2s; d = d2; off = i - Q1; }
    else             { s = w3s; d = d3; off = i - Q2; }
    const float4 v = ((const float4*)s)[off];
    ushort4 o;
    o.x = f2bf(v.x); o.y = f2bf(v.y); o.z = f2bf(v.z); o.w = f2bf(v.w);
    ((ushort4*)d)[off] = o;
    return;
  }
  const int row = bid - CVT_BLOCKS;
  const float4 v = ((const float4*)(x + (size_t)row * EMB))[t];
  float sm = v.x + v.y + v.z + v.w;
  float sq = v.x * v.x + v.y * v.y + v.z * v.z + v.w * v.w;
#pragma unroll
  for (int off = 1; off < 64; off <<= 1) { sm += __shfl_xor(sm, off); sq += __shfl_xor(sq, off); }
  if ((t & 63) == 0) { red[t >> 6] = sm; red[4 + (t >> 6)] = sq; }
  __syncthreads();
  sm = red[0] + red[1] + red[2] + red[3];
  sq = red[4] + red[5] + red[6] + red[7];
  const float mu = sm * (1.f / EMB);
  const float rs = rsqrtf(sq * (1.f / EMB) - mu * mu + 1e-5f);
  const float4 wv = ((const float4*)ln_w)[t];
  const float4 bv = ((const float4*)ln_b)[t];
  ushort4 o;
  o.x = f2bf((v.x - mu) * rs * wv.x + bv.x);
  o.y = f2bf((v.y - mu) * rs * wv.y + bv.y);
  o.z = f2bf((v.z - mu) * rs * wv.z + bv.z);
  o.w = f2bf((v.w - mu) * rs * wv.w + bv.w);
  ((ushort4*)(h + (size_t)row * EMB))[t] = o;
}

// ---------------- sliding-window causal attention, flash-style
__global__ __launch_bounds__(256)
void attn_win(const unsigned short* __restrict__ qkv, const unsigned short* __restrict__ vT,
              unsigned short* __restrict__ aout)
{
  __shared__ unsigned short Ks[64 * 136];
  __shared__ unsigned short Vt[128 * 64];
  __shared__ unsigned short Ps[4 * 16 * 72];
  const int bh = blockIdx.y;
  const int b = bh >> 3, hh = bh & 7;
  const int q0 = blockIdx.x << 6;
  const int tid = threadIdx.x, lane = tid & 63, w = tid >> 6;
  const int l15 = lane & 15, lhi = lane >> 4;
  const size_t base = (size_t)b * 2048 * 3072;

  s16x8 qf[4];
  {
    const unsigned short* qp = qkv + base + (size_t)(q0 + w * 16 + l15) * 3072 + hh * 128 + lhi * 8;
#pragma unroll
    for (int ks = 0; ks < 4; ++ks) qf[ks] = *(const s16x8*)(qp + ks * 32);
  }

  const int vrow = tid >> 3;
  const int vcol = (((tid & 7) ^ ((tid >> 3) & 7)) << 4);
  const char* vTbase = (const char*)(vT + (size_t)(hh * 128 + vrow) * 4096) + vcol;
  char* vdst = (char*)&Vt[0] + (w << 10);
  const char* pVrow = (const char*)&Vt[0] + l15 * 128;
  const int vxor = (l15 & 7) << 4;

  f32x4 o[8];
#pragma unroll
  for (int n = 0; n < 8; ++n)
#pragma unroll
    for (int j = 0; j < 4; ++j) o[n][j] = 0.f;
  float mrow[4] = {-1e30f, -1e30f, -1e30f, -1e30f};
  float lrow[4] = {0.f, 0.f, 0.f, 0.f};

  for (int t = 0; t < 5; ++t) {
    const int kt0 = q0 - 256 + t * 64;
    if (kt0 < 0) continue;
    __syncthreads();
    {
      const unsigned short* kg = qkv + base + (size_t)kt0 * 3072 + 1024 + hh * 128;
#pragma unroll
      for (int i = 0; i < 4; ++i) {
        const int c = tid + i * 256;
        const int r = c >> 4, cc = (c & 15) << 3;
        *(s16x8*)(Ks + r * 136 + cc) = *(const s16x8*)(kg + (size_t)r * 3072 + cc);
      }
      const char* vg = vTbase + (size_t)(b * 2048 + kt0) * 2;
#pragma unroll
      for (int c = 0; c < 4; ++c)
        GLOAD_LDS16(vg + (size_t)(c * 32) * 8192, vdst + c * 4096);
    }
    __syncthreads();

    f32x4 s[4];
#pragma unroll
    for (int n = 0; n < 4; ++n)
#pragma unroll
      for (int j = 0; j < 4; ++j) s[n][j] = 0.f;
    __builtin_amdgcn_s_setprio(1);
#pragma unroll
    for (int ks = 0; ks < 4; ++ks) {
#pragma unroll
      for (int n = 0; n < 4; ++n) {
        s16x8 kf = *(const s16x8*)(Ks + (n * 16 + l15) * 136 + ks * 32 + lhi * 8);
        s[n] = __builtin_amdgcn_mfma_f32_16x16x32_bf16(qf[ks], kf, s[n], 0, 0, 0);
      }
    }
    __builtin_amdgcn_s_setprio(0);
    const bool mlo = (t == 0);
    const bool mhi = (kt0 == q0);
#pragma unroll
    for (int n = 0; n < 4; ++n) {
      const int kcol = n * 16 + l15;
#pragma unroll
      for (int j = 0; j < 4; ++j) {
        const int qrow = w * 16 + lhi * 4 + j;
        float v = s[n][j] * 0.08838834764831845f;
        if ((mlo && kcol < qrow) || (mhi && kcol > qrow)) v = -1e30f;
        s[n][j] = v;
      }
    }
    float alpha[4];
#pragma unroll
    for (int j = 0; j < 4; ++j) {
      float mx = fmaxf(fmaxf(s[0][j], s[1][j]), fmaxf(s[2][j], s[3][j]));
#pragma unroll
      for (int off = 1; off < 16; off <<= 1) mx = fmaxf(mx, __shfl_xor(mx, off));
      const float mn = fmaxf(mrow[j], mx);
      alpha[j] = __expf(mrow[j] - mn);
      mrow[j] = mn;
    }
    float rowsum[4] = {0.f, 0.f, 0.f, 0.f};
#pragma unroll
    for (int n = 0; n < 4; ++n)
#pragma unroll
      for (int j = 0; j < 4; ++j) {
        const float p = __expf(s[n][j] - mrow[j]);
        rowsum[j] += p;
        Ps[(w * 16 + lhi * 4 + j) * 72 + n * 16 + l15] = f2bf(p);
      }
#pragma unroll
    for (int j = 0; j < 4; ++j) {
      float rs = rowsum[j];
#pragma unroll
      for (int off = 1; off < 16; off <<= 1) rs += __shfl_xor(rs, off);
      lrow[j] = lrow[j] * alpha[j] + rs;
    }
#pragma unroll
    for (int n = 0; n < 8; ++n)
#pragma unroll
      for (int j = 0; j < 4; ++j) o[n][j] *= alpha[j];
    __builtin_amdgcn_s_setprio(1);
#pragma unroll
    for (int ks = 0; ks < 2; ++ks) {
      const s16x8 pf = *(const s16x8*)(Ps + (w * 16 + l15) * 72 + ks * 32 + lhi * 8);
      const int cc = (ks * 64 + lhi * 16) ^ vxor;
#pragma unroll
      for (int n = 0; n < 8; ++n) {
        const s16x8 vf = *(const s16x8*)(pVrow + n * 2048 + cc);
        o[n] = __builtin_amdgcn_mfma_f32_16x16x32_bf16(pf, vf, o[n], 0, 0, 0);
      }
    }
    __builtin_amdgcn_s_setprio(0);
  }
  unsigned short* op = aout + (size_t)(b * 2048 + q0 + w * 16) * 1024 + hh * 128;
#pragma unroll
  for (int n = 0; n < 8; ++n)
#pragma unroll
    for (int j = 0; j < 4; ++j)
      op[(size_t)(lhi * 4 + j) * 1024 + n * 16 + l15] = f2bf(o[n][j] / lrow[j]);
}

extern "C" void kernel_launch(void* const* d_in, const int* in_sizes, int n_in,
                              void* d_out, int out_size, void* d_ws, size_t ws_size,
                              hipStream_t stream)
{
  (void)in_sizes; (void)n_in; (void)out_size; (void)ws_size;
  const float* x         = (const float*)d_in[0];
  const float* ln1_w     = (const float*)d_in[1];
  const float* ln1_b     = (const float*)d_in[2];
  const float* ln2_w     = (const float*)d_in[3];
  const float* ln2_b     = (const float*)d_in[4];
  const float* in_proj_w = (const float*)d_in[5];
  const float* in_proj_b = (const float*)d_in[6];
  const float* out_w     = (const float*)d_in[7];
  const float* out_b     = (const float*)d_in[8];
  const float* w1        = (const float*)d_in[9];
  const float* b1        = (const float*)d_in[10];
  const float* w2        = (const float*)d_in[11];
  const float* b2        = (const float*)d_in[12];
  float* out = (float*)d_out;

  char* ws = (char*)d_ws;
  unsigned short* h    = (unsigned short*)(ws);
  unsigned short* wqkv = (unsigned short*)(ws + (8u << 20));
  unsigned short* wout = (unsigned short*)(ws + (14u << 20));
  unsigned short* w1b  = (unsigned short*)(ws + (16u << 20));
  unsigned short* w2b  = (unsigned short*)(ws + (24u << 20));
  unsigned short* qkv  = (unsigned short*)(ws + (32u << 20));
  unsigned short* aout = (unsigned short*)(ws + (56u << 20));
  unsigned short* h2   = (unsigned short*)(ws + (64u << 20));
  unsigned short* m_in = (unsigned short*)(ws + (80u << 20));
  unsigned short* act  = (unsigned short*)(ws + (88u << 20));
  unsigned short* part_op = (unsigned short*)(ws + (88u << 20));
  unsigned short* part_m2 = (unsigned short*)(ws + (32u << 20));
  unsigned short* vT   = (unsigned short*)(ws + (128u << 20));

  // 1: weight cvt + LN1 (merged)
  prep<<<dim3(CVT_BLOCKS + TOK), 256, 0, stream>>>(
      in_proj_w, out_w, w1, w2, wqkv, wout, w1b, w2b, x, ln1_w, ln1_b, h);

  // 2: QKV 256^2 BK64 (control), grid 192; V third -> vT only
  gemm256<0, 0, 16, 1><<<dim3(16 * 12), 512, 0, stream>>>(
      h, wqkv, in_proj_b, qkv, 4096, 3072, 1024, vT);

  // 3: attention (V from vT via gload_lds)
  attn_win<<<dim3(32, 16), 256, 0, stream>>>(qkv, vT, aout);

  // 4: out-proj split-K=4 BK64 (control) -> partials
  gemm256<0, 1, 4, 0><<<dim3(16 * 4, 4), 512, 0, stream>>>(
      aout, wout, nullptr, part_op, 4096, 1024, 1024, nullptr);

  // 5: reduce + residual + LN2 (h2 bf16)
  reduce_ln<<<dim3(TOK), 256, 0, stream>>>(part_op, x, out_b, ln2_w, ln2_b, h2, m_in, 4);

  // 6: MLP1 256^2 BK=32 EXPERIMENT (2 blocks/CU), grid 256, NT=32, relu
  gemm256_b32<1, 32><<<dim3(16 * 16), 512, 0, stream>>>(
      m_in, w1b, b1, act, 4096, 4096, 1024);

  // 7: MLP2 split-K=4 BK64 (control) -> partials
  gemm256<0, 1, 16, 0><<<dim3(16 * 4, 4), 512, 0, stream>>>(
      act, w2b, nullptr, part_m2, 4096, 1024, 4096, nullptr);

  // 8: reduce + bias + residual(bf16) -> fp32 out
  reduce_add<<<dim3(4096 * 1024 / 4 / 256), 256, 0, stream>>>(
      part_m2, h2, b2, out, 4096 * 1024, 1024, 4);
}